// Round 2
// baseline (132.581 us; speedup 1.0000x reference)
//
#include <hip/hip_runtime.h>
#include <hip/hip_bf16.h>

namespace {
constexpr int N = 1024;
constexpr int D = 128;
constexpr int E = 32768;
constexpr int R = 32;

// ---- edge pass 1: counts + degrees (int atomics) ----
__global__ void k_edges1(const int* __restrict__ ei, int* cnt, int* deg){
  int e = blockIdx.x*256 + threadIdx.x;
  if(e < E){
    int s = ei[e], d = ei[E+e];
    atomicAdd(&cnt[d], 1);
    atomicAdd(&deg[s], 1);
    atomicAdd(&deg[d], 1);
  }
}

// ---- exclusive scan of cnt -> CSR offsets (single block) ----
__global__ __launch_bounds__(1024) void k_scan(const int* __restrict__ cnt, int* off, int* cur){
  __shared__ int s[N];
  int t = threadIdx.x;
  s[t] = cnt[t];
  __syncthreads();
  for(int d = 1; d < N; d <<= 1){
    int v = (t >= d) ? s[t-d] : 0;
    __syncthreads();
    s[t] += v;
    __syncthreads();
  }
  int excl = (t == 0) ? 0 : s[t-1];
  off[t] = excl;
  cur[t] = excl;
  if(t == N-1) off[N] = s[t];
}

// ---- edge pass 2: fill buckets ----
__global__ void k_edges2(const int* __restrict__ ei, int* cur, int* bucket){
  int e = blockIdx.x*256 + threadIdx.x;
  if(e < E){
    int s = ei[e], d = ei[E+e];
    int p = atomicAdd(&cur[d], 1);
    bucket[p] = s;
  }
}

// ---- GNN: mean-aggregate + two 128x128 GEMV rows + GELU + score MLP ----
__global__ __launch_bounds__(128) void k_gnn(const float* __restrict__ x,
     const float* __restrict__ Wl, const float* __restrict__ bl,
     const float* __restrict__ Wr, const float* __restrict__ W1,
     const float* __restrict__ b1, const float* __restrict__ W2,
     const float* __restrict__ b2,
     const int* __restrict__ off, const int* __restrict__ bucket,
     const int* __restrict__ deg,
     float* __restrict__ xg, float* __restrict__ scores){
  int n = blockIdx.x, t = threadIdx.x;
  __shared__ float smean[D], sx[D], sxg[D];
  int beg = off[n], end = off[n+1];
  float acc = 0.f;
  for(int j = beg; j < end; ++j){
    int s = bucket[j];
    acc += x[s*D + t];
  }
  int c = end - beg;
  smean[t] = acc / (float)(c > 1 ? c : 1);
  sx[t] = x[n*D + t];
  __syncthreads();
  float a = 0.f, b = 0.f;
  for(int k = 0; k < D; ++k){
    a += smean[k] * Wl[t*D + k];
    b += sx[k]    * Wr[t*D + k];
  }
  float v = a + bl[t] + b + sx[t];
  float g = 0.5f * v * (1.0f + erff(v * 0.7071067811865475f));
  xg[n*D + t] = g;
  sxg[t] = g;
  __syncthreads();
  // scores: threads 0..31 each compute one hidden unit of the R=32 MLP
  float part = 0.f;
  if(t < R){
    float h = 0.f;
    for(int k = 0; k < D; ++k) h += sxg[k] * W1[t*D + k];
    h += b1[t];
    h = fmaxf(h, 0.f);
    part = h * W2[t];
  }
  part += __shfl_down(part, 16);
  part += __shfl_down(part, 8);
  part += __shfl_down(part, 4);
  part += __shfl_down(part, 2);
  part += __shfl_down(part, 1);
  if(t == 0) scores[n] = part + b2[0] + (float)deg[n];
}

// ---- bitonic argsort: descending score, ties -> ascending index (stable) ----
__global__ __launch_bounds__(1024) void k_sort(const float* __restrict__ scores, int* sidx){
  __shared__ unsigned long long keys[N];
  int t = threadIdx.x;
  unsigned int u = __float_as_uint(scores[t]);
  u = (u >> 31) ? ~u : (u | 0x80000000u);   // monotonic float->uint (ascending)
  unsigned int ks = ~u;                      // invert: ascending sort == descending score
  keys[t] = ((unsigned long long)ks << 32) | (unsigned int)t; // low bits: index (asc on ties)
  __syncthreads();
  for(int k = 2; k <= N; k <<= 1){
    for(int j = k >> 1; j > 0; j >>= 1){
      int ixj = t ^ j;
      if(ixj > t){
        bool up = ((t & k) == 0);
        unsigned long long a = keys[t], b = keys[ixj];
        if((a > b) == up){ keys[t] = b; keys[ixj] = a; }
      }
      __syncthreads();
    }
  }
  sidx[t] = (int)(keys[t] & 0xFFFFFFFFu);
}

// ---- projections: delta_raw/Cs/res rows of Wp, then delta = softplus(.@Wd^T+bd); S1,S2 ----
__global__ __launch_bounds__(128) void k_proj(const float* __restrict__ xg,
     const float* __restrict__ Wp, const float* __restrict__ Wd, const float* __restrict__ bd,
     float* __restrict__ delta, float* __restrict__ res,
     float* __restrict__ s1, float* __restrict__ s2){
  int n = blockIdx.x, t = threadIdx.x;
  __shared__ float sxr[D], sdr[D];
  sxr[t] = xg[n*D + t];
  __syncthreads();
  float dr = 0.f, c = 0.f, r = 0.f;
  for(int k = 0; k < D; ++k){
    float xv = sxr[k];
    dr += xv * Wp[(t)*D + k];          // rows 0..127   -> delta_raw
    c  += xv * Wp[(2*D + t)*D + k];    // rows 256..383 -> Cs
    r  += xv * Wp[(3*D + t)*D + k];    // rows 384..511 -> residual
  }
  sdr[t] = dr;
  res[n*D + t] = r;
  atomicAdd(&s1[t], sxr[t] * c);
  atomicAdd(&s2[t], c);
  __syncthreads();
  float d2 = 0.f;
  for(int k = 0; k < D; ++k) d2 += sdr[k] * Wd[t*D + k];
  d2 += bd[t];
  float sp = (d2 > 20.f) ? d2 : log1pf(expf(d2));
  delta[n*D + t] = sp;
}

// ---- per-head inclusive cumsum over sorted order ----
__global__ __launch_bounds__(1024) void k_cumsum(const float* __restrict__ delta,
     const int* __restrict__ sidx, const float* __restrict__ Bp, float* __restrict__ pfx){
  int h = blockIdx.x, t = threadIdx.x;
  __shared__ float s[N];
  float bv = Bp[h];
  s[t] = delta[sidx[t]*D + h] * bv;
  __syncthreads();
  for(int d = 1; d < N; d <<= 1){
    float v = (t >= d) ? s[t-d] : 0.f;
    __syncthreads();
    s[t] += v;
    __syncthreads();
  }
  pfx[t*D + h] = s[t];
}

// ---- final: y + res*Dp, LayerNorm over D, un-permute, add x, f32 out ----
__global__ __launch_bounds__(128) void k_final(
    const float* __restrict__ delta, const float* __restrict__ res,
    const float* __restrict__ pfx, const int* __restrict__ sidx,
    const float* __restrict__ s1, const float* __restrict__ s2,
    const float* __restrict__ A, const float* __restrict__ Bp,
    const float* __restrict__ Dp, const float* __restrict__ x,
    float* __restrict__ out){
  int l = blockIdx.x, h = threadIdx.x;
  int i = sidx[l];
  float dlt = delta[i*D + h];
  float dA = expf(dlt * A[h]) * Bp[h];
  float o = dA * s1[h] + pfx[l*D + h] * s2[h] + res[i*D + h] * Dp[0];
  __shared__ float sm1[2], sm2[2];
  float v = o;
  v += __shfl_down(v, 32); v += __shfl_down(v, 16); v += __shfl_down(v, 8);
  v += __shfl_down(v, 4);  v += __shfl_down(v, 2);  v += __shfl_down(v, 1);
  int wid = h >> 6, lane = h & 63;
  if(lane == 0) sm1[wid] = v;
  __syncthreads();
  float mean = (sm1[0] + sm1[1]) * (1.0f/(float)D);
  float cdev = o - mean;
  float cv = cdev * cdev;
  cv += __shfl_down(cv, 32); cv += __shfl_down(cv, 16); cv += __shfl_down(cv, 8);
  cv += __shfl_down(cv, 4);  cv += __shfl_down(cv, 2);  cv += __shfl_down(cv, 1);
  if(lane == 0) sm2[wid] = cv;
  __syncthreads();
  float var = (sm2[0] + sm2[1]) * (1.0/(float)D);
  float nrm = cdev * rsqrtf(var + 1e-5f);
  out[i*D + h] = x[i*D + h] + nrm;
}

} // namespace

extern "C" void kernel_launch(void* const* d_in, const int* in_sizes, int n_in,
                              void* d_out, int out_size, void* d_ws, size_t ws_size,
                              hipStream_t stream){
  const float* x   = (const float*)d_in[0];
  const int*   ei  = (const int*)d_in[1];
  const float* Wl  = (const float*)d_in[2];
  const float* bl  = (const float*)d_in[3];
  const float* Wr  = (const float*)d_in[4];
  const float* W1  = (const float*)d_in[5];
  const float* b1  = (const float*)d_in[6];
  const float* W2  = (const float*)d_in[7];
  const float* b2  = (const float*)d_in[8];
  const float* Wp  = (const float*)d_in[9];
  const float* A   = (const float*)d_in[10];
  const float* Bp  = (const float*)d_in[11];
  const float* Dp  = (const float*)d_in[12];
  const float* Wd  = (const float*)d_in[13];
  const float* bd  = (const float*)d_in[14];

  char* ws = (char*)d_ws;
  size_t o = 0;
  auto alloc = [&](size_t bytes)->char*{
    char* p = ws + o;
    o = (o + bytes + 255) & ~(size_t)255;
    return p;
  };
  // zero-initialized region (one memset)
  int*   cnt    = (int*)  alloc(N*4);
  int*   deg    = (int*)  alloc(N*4);
  float* s1     = (float*)alloc(D*4);
  float* s2     = (float*)alloc(D*4);
  size_t zbytes = o;
  int*   off    = (int*)  alloc((N+1)*4);
  int*   cur    = (int*)  alloc(N*4);
  int*   bucket = (int*)  alloc(E*4);
  float* xg     = (float*)alloc((size_t)N*D*4);
  float* scores = (float*)alloc(N*4);
  int*   sidx   = (int*)  alloc(N*4);
  float* delta  = (float*)alloc((size_t)N*D*4);
  float* res    = (float*)alloc((size_t)N*D*4);
  float* pfx    = (float*)alloc((size_t)N*D*4);
  (void)ws_size; (void)in_sizes; (void)n_in; (void)out_size;

  hipMemsetAsync(d_ws, 0, zbytes, stream);
  k_edges1<<<(E+255)/256, 256, 0, stream>>>(ei, cnt, deg);
  k_scan  <<<1, 1024, 0, stream>>>(cnt, off, cur);
  k_edges2<<<(E+255)/256, 256, 0, stream>>>(ei, cur, bucket);
  k_gnn   <<<N, 128, 0, stream>>>(x, Wl, bl, Wr, W1, b1, W2, b2, off, bucket, deg, xg, scores);
  k_sort  <<<1, 1024, 0, stream>>>(scores, sidx);
  k_proj  <<<N, 128, 0, stream>>>(xg, Wp, Wd, bd, delta, res, s1, s2);
  k_cumsum<<<D, 1024, 0, stream>>>(delta, sidx, Bp, pfx);
  k_final <<<N, 128, 0, stream>>>(delta, res, pfx, sidx, s1, s2, A, Bp, Dp, x, (float*)d_out);
}

// Round 3
// 113.351 us; speedup vs baseline: 1.1696x; 1.1696x over previous
//
#include <hip/hip_runtime.h>
#include <hip/hip_bf16.h>

namespace {
constexpr int N = 1024;
constexpr int D = 128;
constexpr int E = 32768;
constexpr int TILE = 8;          // nodes per block in fused kernel

// ---- edge pass 1: counts + degrees (int atomics) ----
__global__ void k_edges1(const int* __restrict__ ei, int* cnt, int* deg){
  int e = blockIdx.x*256 + threadIdx.x;
  if(e < E){
    int s = ei[e], d = ei[E+e];
    atomicAdd(&cnt[d], 1);
    atomicAdd(&deg[s], 1);
    atomicAdd(&deg[d], 1);
  }
}

// ---- exclusive scan of cnt -> CSR offsets (single block) ----
__global__ __launch_bounds__(1024) void k_scan(const int* __restrict__ cnt, int* off, int* cur){
  __shared__ int s[N];
  int t = threadIdx.x;
  s[t] = cnt[t];
  __syncthreads();
  for(int d = 1; d < N; d <<= 1){
    int v = (t >= d) ? s[t-d] : 0;
    __syncthreads();
    s[t] += v;
    __syncthreads();
  }
  int excl = (t == 0) ? 0 : s[t-1];
  off[t] = excl;
  cur[t] = excl;
  if(t == N-1) off[N] = s[t];
}

// ---- edge pass 2: fill buckets ----
__global__ void k_edges2(const int* __restrict__ ei, int* cur, int* bucket){
  int e = blockIdx.x*256 + threadIdx.x;
  if(e < E){
    int s = ei[e], d = ei[E+e];
    int p = atomicAdd(&cur[d], 1);
    bucket[p] = s;
  }
}

// ---- fused: mean-agg + GNN GEMVs + GELU + score MLP + Wp/Wd projections + S1/S2 ----
// block = 256 threads = (feature f = tid&127) x (node-half hh = tid>>7), TILE=8 nodes/block.
// Each thread owns 4 nodes (q=0..3, p = hh*4+q) so every weight float4 is reused 4x.
__global__ __launch_bounds__(256) void k_fused(
    const float* __restrict__ x,
    const float* __restrict__ Wl, const float* __restrict__ bl,
    const float* __restrict__ Wr,
    const float* __restrict__ W1, const float* __restrict__ b1,
    const float* __restrict__ W2, const float* __restrict__ b2,
    const float* __restrict__ Wp, const float* __restrict__ Wd,
    const float* __restrict__ bd,
    const int* __restrict__ off, const int* __restrict__ bucket,
    const int* __restrict__ deg,
    float* __restrict__ delta, float* __restrict__ res,
    float* __restrict__ scores, float* __restrict__ s1, float* __restrict__ s2)
{
  __shared__ float sx[TILE][D];
  __shared__ float smean[TILE][D];
  __shared__ float sxg[TILE][D];
  __shared__ float sdr[TILE][D];
  int tid = threadIdx.x;
  int base = blockIdx.x * TILE;

  // load x tile (one float4 per thread)
  {
    float4 v = *(const float4*)&x[base*D + tid*4];
    *(float4*)&sx[0][tid*4] = v;
  }

  int f = tid & 127, hh = tid >> 7;

  // neighbor mean (2 nodes at a time across the block)
  for(int p2 = 0; p2 < TILE/2; ++p2){
    int p = p2*2 + hh;
    int n = base + p;
    int beg = off[n], end = off[n+1];
    float acc = 0.f;
    for(int j = beg; j < end; ++j) acc += x[bucket[j]*D + f];
    int c = end - beg;
    smean[p][f] = acc / (float)(c > 1 ? c : 1);
  }
  __syncthreads();

  // GEMV: v = mean@Wl^T + bl + x@Wr^T + x ; xg = gelu(v)
  int p0 = hh*4;
  {
    float accL[4] = {0,0,0,0}, accR[4] = {0,0,0,0};
    for(int k = 0; k < D; k += 4){
      float4 wl = *(const float4*)&Wl[f*D + k];
      float4 wr = *(const float4*)&Wr[f*D + k];
      #pragma unroll
      for(int q = 0; q < 4; ++q){
        float4 m  = *(const float4*)&smean[p0+q][k];
        float4 xv = *(const float4*)&sx[p0+q][k];
        accL[q] += m.x*wl.x + m.y*wl.y + m.z*wl.z + m.w*wl.w;
        accR[q] += xv.x*wr.x + xv.y*wr.y + xv.z*wr.z + xv.w*wr.w;
      }
    }
    float blf = bl[f];
    #pragma unroll
    for(int q = 0; q < 4; ++q){
      int p = p0 + q;
      float v = accL[q] + accR[q] + blf + sx[p][f];
      float g = 0.5f * v * (1.0f + erff(v * 0.7071067811865475f));
      sxg[p][f] = g;
    }
  }
  __syncthreads();

  // scores: thread = (p = tid>>5 in 0..7, r = tid&31); reduce over r within 32-lane group
  {
    int r = tid & 31, p = tid >> 5;
    float hsum = 0.f;
    for(int k = 0; k < D; k += 4){
      float4 w = *(const float4*)&W1[r*D + k];
      float4 g = *(const float4*)&sxg[p][k];
      hsum += g.x*w.x + g.y*w.y + g.z*w.z + g.w*w.w;
    }
    hsum += b1[r];
    hsum = fmaxf(hsum, 0.f);
    float part = hsum * W2[r];
    part += __shfl_down(part, 16, 32);
    part += __shfl_down(part, 8, 32);
    part += __shfl_down(part, 4, 32);
    part += __shfl_down(part, 2, 32);
    part += __shfl_down(part, 1, 32);
    if(r == 0) scores[base + p] = part + b2[0] + (float)deg[base + p];
  }

  // projections: delta_raw (Wp rows 0..127), Cs (rows 256..383), residual (rows 384..511)
  {
    const float* WpC = Wp + 2*D*D;
    const float* WpR = Wp + 3*D*D;
    float accDl[4] = {0,0,0,0}, accC[4] = {0,0,0,0}, accR2[4] = {0,0,0,0};
    for(int k = 0; k < D; k += 4){
      float4 wd_ = *(const float4*)&Wp [f*D + k];
      float4 wc  = *(const float4*)&WpC[f*D + k];
      float4 wr2 = *(const float4*)&WpR[f*D + k];
      #pragma unroll
      for(int q = 0; q < 4; ++q){
        float4 g = *(const float4*)&sxg[p0+q][k];
        accDl[q] += g.x*wd_.x + g.y*wd_.y + g.z*wd_.z + g.w*wd_.w;
        accC[q]  += g.x*wc.x  + g.y*wc.y  + g.z*wc.z  + g.w*wc.w;
        accR2[q] += g.x*wr2.x + g.y*wr2.y + g.z*wr2.z + g.w*wr2.w;
      }
    }
    float lS1 = 0.f, lS2 = 0.f;
    #pragma unroll
    for(int q = 0; q < 4; ++q){
      int p = p0 + q, n = base + p;
      res[n*D + f] = accR2[q];
      lS1 += sxg[p][f] * accC[q];
      lS2 += accC[q];
      sdr[p][f] = accDl[q];
    }
    atomicAdd(&s1[f], lS1);
    atomicAdd(&s2[f], lS2);
  }
  __syncthreads();

  // delta = softplus(delta_raw @ Wd^T + bd)
  {
    float accW[4] = {0,0,0,0};
    for(int k = 0; k < D; k += 4){
      float4 w = *(const float4*)&Wd[f*D + k];
      #pragma unroll
      for(int q = 0; q < 4; ++q){
        float4 dv = *(const float4*)&sdr[p0+q][k];
        accW[q] += dv.x*w.x + dv.y*w.y + dv.z*w.z + dv.w*w.w;
      }
    }
    float bdf = bd[f];
    #pragma unroll
    for(int q = 0; q < 4; ++q){
      float d2 = accW[q] + bdf;
      float sp = (d2 > 20.f) ? d2 : log1pf(expf(d2));
      delta[(base + p0 + q)*D + f] = sp;
    }
  }
}

// ---- bitonic argsort: descending score, ties -> ascending index (stable) ----
__global__ __launch_bounds__(1024) void k_sort(const float* __restrict__ scores, int* sidx){
  __shared__ unsigned long long keys[N];
  int t = threadIdx.x;
  unsigned int u = __float_as_uint(scores[t]);
  u = (u >> 31) ? ~u : (u | 0x80000000u);
  unsigned int ks = ~u;
  keys[t] = ((unsigned long long)ks << 32) | (unsigned int)t;
  __syncthreads();
  for(int k = 2; k <= N; k <<= 1){
    for(int j = k >> 1; j > 0; j >>= 1){
      int ixj = t ^ j;
      if(ixj > t){
        bool up = ((t & k) == 0);
        unsigned long long a = keys[t], b = keys[ixj];
        if((a > b) == up){ keys[t] = b; keys[ixj] = a; }
      }
      __syncthreads();
    }
  }
  sidx[t] = (int)(keys[t] & 0xFFFFFFFFu);
}

// ---- per-head inclusive cumsum over sorted order (wave shuffle scan) ----
__global__ __launch_bounds__(1024) void k_cumsum(const float* __restrict__ delta,
     const int* __restrict__ sidx, const float* __restrict__ Bp, float* __restrict__ pfxT){
  int h = blockIdx.x, t = threadIdx.x;
  float v = delta[sidx[t]*D + h] * Bp[h];
  int lane = t & 63, w = t >> 6;
  #pragma unroll
  for(int o2 = 1; o2 < 64; o2 <<= 1){
    float nb = __shfl_up(v, o2, 64);
    if(lane >= o2) v += nb;
  }
  __shared__ float wsum[16];
  if(lane == 63) wsum[w] = v;
  __syncthreads();
  float pref = 0.f;
  #pragma unroll
  for(int i = 0; i < 16; ++i){
    float s = wsum[i];
    if(i < w) pref += s;
  }
  pfxT[h*N + t] = v + pref;   // coalesced write
}

// ---- final: y + res*Dp, LayerNorm over D, un-permute, add x ----
__global__ __launch_bounds__(128) void k_final(
    const float* __restrict__ delta, const float* __restrict__ res,
    const float* __restrict__ pfxT, const int* __restrict__ sidx,
    const float* __restrict__ s1, const float* __restrict__ s2,
    const float* __restrict__ A, const float* __restrict__ Bp,
    const float* __restrict__ Dp, const float* __restrict__ x,
    float* __restrict__ out){
  int l = blockIdx.x, h = threadIdx.x;
  int i = sidx[l];
  float dlt = delta[i*D + h];
  float dAv = expf(dlt * A[h]) * Bp[h];
  float o = dAv * s1[h] + pfxT[h*N + l] * s2[h] + res[i*D + h] * Dp[0];
  __shared__ float sm1[2], sm2[2];
  float v = o;
  v += __shfl_down(v, 32); v += __shfl_down(v, 16); v += __shfl_down(v, 8);
  v += __shfl_down(v, 4);  v += __shfl_down(v, 2);  v += __shfl_down(v, 1);
  int wid = h >> 6, lane = h & 63;
  if(lane == 0) sm1[wid] = v;
  __syncthreads();
  float mean = (sm1[0] + sm1[1]) * (1.0f/(float)D);
  float cdev = o - mean;
  float cv = cdev * cdev;
  cv += __shfl_down(cv, 32); cv += __shfl_down(cv, 16); cv += __shfl_down(cv, 8);
  cv += __shfl_down(cv, 4);  cv += __shfl_down(cv, 2);  cv += __shfl_down(cv, 1);
  if(lane == 0) sm2[wid] = cv;
  __syncthreads();
  float var = (sm2[0] + sm2[1]) * (1.0f/(float)D);
  float nrm = cdev * rsqrtf(var + 1e-5f);
  out[i*D + h] = x[i*D + h] + nrm;
}

} // namespace

extern "C" void kernel_launch(void* const* d_in, const int* in_sizes, int n_in,
                              void* d_out, int out_size, void* d_ws, size_t ws_size,
                              hipStream_t stream){
  const float* x   = (const float*)d_in[0];
  const int*   ei  = (const int*)d_in[1];
  const float* Wl  = (const float*)d_in[2];
  const float* bl  = (const float*)d_in[3];
  const float* Wr  = (const float*)d_in[4];
  const float* W1  = (const float*)d_in[5];
  const float* b1  = (const float*)d_in[6];
  const float* W2  = (const float*)d_in[7];
  const float* b2  = (const float*)d_in[8];
  const float* Wp  = (const float*)d_in[9];
  const float* A   = (const float*)d_in[10];
  const float* Bp  = (const float*)d_in[11];
  const float* Dp  = (const float*)d_in[12];
  const float* Wd  = (const float*)d_in[13];
  const float* bd  = (const float*)d_in[14];

  char* ws = (char*)d_ws;
  size_t o = 0;
  auto alloc = [&](size_t bytes)->char*{
    char* p = ws + o;
    o = (o + bytes + 255) & ~(size_t)255;
    return p;
  };
  // zero-initialized region (one memset)
  int*   cnt    = (int*)  alloc(N*4);
  int*   deg    = (int*)  alloc(N*4);
  float* s1     = (float*)alloc(D*4);
  float* s2     = (float*)alloc(D*4);
  size_t zbytes = o;
  int*   off    = (int*)  alloc((N+1)*4);
  int*   cur    = (int*)  alloc(N*4);
  int*   bucket = (int*)  alloc(E*4);
  float* scores = (float*)alloc(N*4);
  int*   sidx   = (int*)  alloc(N*4);
  float* delta  = (float*)alloc((size_t)N*D*4);
  float* res    = (float*)alloc((size_t)N*D*4);
  float* pfxT   = (float*)alloc((size_t)N*D*4);
  (void)ws_size; (void)in_sizes; (void)n_in; (void)out_size;

  hipMemsetAsync(d_ws, 0, zbytes, stream);
  k_edges1<<<(E+255)/256, 256, 0, stream>>>(ei, cnt, deg);
  k_scan  <<<1, 1024, 0, stream>>>(cnt, off, cur);
  k_edges2<<<(E+255)/256, 256, 0, stream>>>(ei, cur, bucket);
  k_fused <<<N/TILE, 256, 0, stream>>>(x, Wl, bl, Wr, W1, b1, W2, b2, Wp, Wd, bd,
                                       off, bucket, deg, delta, res, scores, s1, s2);
  k_sort  <<<1, 1024, 0, stream>>>(scores, sidx);
  k_cumsum<<<D, 1024, 0, stream>>>(delta, sidx, Bp, pfxT);
  k_final <<<N, 128, 0, stream>>>(delta, res, pfxT, sidx, s1, s2, A, Bp, Dp, x, (float*)d_out);
}

// Round 4
// 90.051 us; speedup vs baseline: 1.4723x; 1.2587x over previous
//
#include <hip/hip_runtime.h>

namespace {
constexpr int N = 1024;
constexpr int D = 128;
constexpr int E = 32768;
constexpr int TILE = 4;      // nodes per fused block -> grid = 256 = #CUs
constexpr int WPAD = 36;     // 144B rows: 16B-aligned, banks spread (4f+4k)%32

// ---- edge pass 1: counts + degrees (int atomics) ----
__global__ void k_edges1(const int* __restrict__ ei, int* cnt, int* deg){
  int e = blockIdx.x*256 + threadIdx.x;
  if(e < E){
    int s = ei[e], d = ei[E+e];
    atomicAdd(&cnt[d], 1);
    atomicAdd(&deg[s], 1);
    atomicAdd(&deg[d], 1);
  }
}

// ---- exclusive scan of cnt -> CSR offsets (wave shuffle scan, 1 barrier) ----
__global__ __launch_bounds__(1024) void k_scan(const int* __restrict__ cnt, int* off, int* cur){
  int t = threadIdx.x;
  int v = cnt[t], own = v;
  int lane = t & 63, w = t >> 6;
  #pragma unroll
  for(int o2 = 1; o2 < 64; o2 <<= 1){
    int nb = __shfl_up(v, o2, 64);
    if(lane >= o2) v += nb;
  }
  __shared__ int wsum[16];
  if(lane == 63) wsum[w] = v;
  __syncthreads();
  int pref = 0;
  #pragma unroll
  for(int i = 0; i < 16; ++i){ int sv = wsum[i]; if(i < w) pref += sv; }
  int incl = v + pref, excl = incl - own;
  off[t] = excl; cur[t] = excl;
  if(t == N-1) off[N] = incl;
}

// ---- edge pass 2: fill buckets ----
__global__ void k_edges2(const int* __restrict__ ei, int* cur, int* bucket){
  int e = blockIdx.x*256 + threadIdx.x;
  if(e < E){
    int s = ei[e], d = ei[E+e];
    int p = atomicAdd(&cur[d], 1);
    bucket[p] = s;
  }
}

// ---- fused GEMM chain: mean-agg + (Wl,Wr)+gelu + scores + Wp(3 slices) + Wd ----
// 256 blocks x 256 thr. thread = (f = tid&127, hh = tid>>7); owns nodes p0, p0+1.
// Weights double-buffered in LDS via async-split staging (load->compute->write).
__global__ __launch_bounds__(256, 2) void k_fused(
    const float* __restrict__ x,
    const float* __restrict__ Wl, const float* __restrict__ bl,
    const float* __restrict__ Wr,
    const float* __restrict__ W1, const float* __restrict__ b1,
    const float* __restrict__ W2, const float* __restrict__ b2,
    const float* __restrict__ Wp, const float* __restrict__ Wd,
    const float* __restrict__ bd,
    const int* __restrict__ off, const int* __restrict__ bucket,
    const int* __restrict__ deg,
    float* __restrict__ delta, float* __restrict__ res,
    float* __restrict__ scores, float* __restrict__ s1, float* __restrict__ s2)
{
  __shared__ float sx[TILE][D], smean[TILE][D], sxg[TILE][D], sdr[TILE][D];
  __shared__ float sW[2][D][WPAD];
  int tid = threadIdx.x;
  int base = blockIdx.x * TILE;
  int f = tid & 127, hh = tid >> 7, p0 = hh*2;
  int kk = tid & 31, fb = (tid >> 5) * 16;

  const float* WpA = Wp;
  const float* WpC = Wp + 2*D*D;
  const float* WpR = Wp + 3*D*D;

  // issue chunk-0 staging loads early (latency hides under the gather)
  float tmp[16];
  #pragma unroll
  for(int i = 0; i < 16; ++i) tmp[i] = Wl[(fb+i)*D + kk];

  // x tile -> LDS
  if(tid < 128) *(float4*)&sx[0][tid*4] = *(const float4*)&x[base*D + tid*4];

  // neighbor mean for 2 nodes (4-unrolled gather, coalesced 256B rows)
  for(int p = p0; p < p0+2; ++p){
    int n = base + p, beg = off[n], end = off[n+1];
    float a0 = 0.f, a1 = 0.f, a2 = 0.f, a3 = 0.f;
    int j = beg;
    for(; j + 3 < end; j += 4){
      int i0 = bucket[j], i1 = bucket[j+1], i2 = bucket[j+2], i3 = bucket[j+3];
      a0 += x[i0*D + f]; a1 += x[i1*D + f];
      a2 += x[i2*D + f]; a3 += x[i3*D + f];
    }
    for(; j < end; ++j) a0 += x[bucket[j]*D + f];
    int c = end - beg;
    smean[p][f] = (a0+a1+a2+a3) / (float)(c > 1 ? c : 1);
  }

  // write chunk 0 (conflict-free: bank = (4i+kk)%32, fb*4 == 0 mod 32)
  #pragma unroll
  for(int i = 0; i < 16; ++i) sW[0][fb+i][kk] = tmp[i];
  __syncthreads();

  float a0 = 0.f, a1 = 0.f;       // running GEMV accumulators
  float g0 = 0.f, g1 = 0.f;       // gelu outputs kept in regs for S1
  int buf = 0;
  for(int s = 0; s < 24; ++s){
    int m = s >> 2, kc = s & 3;
    // stage-load next chunk into regs (issue BEFORE compute; write after)
    if(s < 23){
      int ns = s + 1, nm = ns >> 2, nkc = ns & 3;
      const float* M = nm==0 ? Wl : nm==1 ? Wr : nm==2 ? WpA : nm==3 ? WpC : nm==4 ? WpR : Wd;
      #pragma unroll
      for(int i = 0; i < 16; ++i) tmp[i] = M[(fb+i)*D + nkc*32 + kk];
    }
    // compute current chunk from LDS
    const float (*sIn)[D] = (m==0) ? smean : (m==1) ? sx : (m<5) ? sxg : sdr;
    int kb = kc*32;
    #pragma unroll
    for(int k4 = 0; k4 < 8; ++k4){
      float4 w   = *(const float4*)&sW[buf][f][k4*4];
      float4 v0  = *(const float4*)&sIn[p0  ][kb + k4*4];
      float4 v1  = *(const float4*)&sIn[p0+1][kb + k4*4];
      a0 += v0.x*w.x + v0.y*w.y + v0.z*w.z + v0.w*w.w;
      a1 += v1.x*w.x + v1.y*w.y + v1.z*w.z + v1.w*w.w;
    }
    // stage-write next chunk (vmcnt satisfied by now)
    if(s < 23){
      #pragma unroll
      for(int i = 0; i < 16; ++i) sW[buf^1][fb+i][kk] = tmp[i];
    }
    // phase epilogues
    if(s == 7){               // x_gnn = meanWl + xWr + bl + x ; gelu
      float blf = bl[f];
      float v0 = a0 + blf + sx[p0][f];
      float v1 = a1 + blf + sx[p0+1][f];
      g0 = 0.5f*v0*(1.0f + erff(v0*0.7071067811865475f));
      g1 = 0.5f*v1*(1.0f + erff(v1*0.7071067811865475f));
      sxg[p0][f] = g0; sxg[p0+1][f] = g1;
      a0 = 0.f; a1 = 0.f;
    } else if(s == 11){       // delta_raw -> sdr
      sdr[p0][f] = a0; sdr[p0+1][f] = a1;
      a0 = 0.f; a1 = 0.f;
    } else if(s == 15){       // Cs -> S1/S2
      atomicAdd(&s1[f], g0*a0 + g1*a1);
      atomicAdd(&s2[f], a0 + a1);
      a0 = 0.f; a1 = 0.f;
    } else if(s == 19){       // residual -> global
      res[(base+p0)*D + f]   = a0;
      res[(base+p0+1)*D + f] = a1;
      a0 = 0.f; a1 = 0.f;
    }
    __syncthreads();
    buf ^= 1;
  }
  // delta = softplus(sdr @ Wd^T + bd)
  {
    float bdf = bd[f];
    float d0 = a0 + bdf, d1 = a1 + bdf;
    float sp0 = (d0 > 20.f) ? d0 : log1pf(expf(d0));
    float sp1 = (d1 > 20.f) ? d1 : log1pf(expf(d1));
    delta[(base+p0)*D + f]   = sp0;
    delta[(base+p0+1)*D + f] = sp1;
  }
  // scores MLP (R=32) + deg
  if(tid < 128){
    int r = tid & 31, p = tid >> 5;
    float h = 0.f;
    #pragma unroll
    for(int k4 = 0; k4 < 32; ++k4){
      float4 w = *(const float4*)&W1[r*D + k4*4];
      float4 g = *(const float4*)&sxg[p][k4*4];
      h += g.x*w.x + g.y*w.y + g.z*w.z + g.w*w.w;
    }
    h += b1[r];
    h = fmaxf(h, 0.f);
    float part = h * W2[r];
    part += __shfl_down(part, 16, 32);
    part += __shfl_down(part, 8, 32);
    part += __shfl_down(part, 4, 32);
    part += __shfl_down(part, 2, 32);
    part += __shfl_down(part, 1, 32);
    if(r == 0) scores[base + p] = part + b2[0] + (float)deg[base + p];
  }
}

__device__ __forceinline__ unsigned long long shflx64(unsigned long long v, int m){
  int lo = __shfl_xor((int)(v & 0xffffffffull), m);
  int hi = __shfl_xor((int)(v >> 32), m);
  return ((unsigned long long)(unsigned int)hi << 32) | (unsigned int)lo;
}

// ---- hybrid bitonic argsort: j>=64 via LDS+barrier, j<=32 in-register shfl ----
__global__ __launch_bounds__(1024) void k_sort(const float* __restrict__ scores, int* sidx){
  __shared__ unsigned long long keys[N];
  int t = threadIdx.x;
  unsigned int u = __float_as_uint(scores[t]);
  u = (u >> 31) ? ~u : (u | 0x80000000u);    // monotone float->uint (ascending)
  unsigned int ks = ~u;                       // descending score
  keys[t] = ((unsigned long long)ks << 32) | (unsigned int)t;
  __syncthreads();
  for(int k = 2; k <= N; k <<= 1){
    for(int j = k >> 1; j >= 64; j >>= 1){
      int ixj = t ^ j;
      if(ixj > t){
        bool up = ((t & k) == 0);
        unsigned long long a = keys[t], b = keys[ixj];
        if((a > b) == up){ keys[t] = b; keys[ixj] = a; }
      }
      __syncthreads();
    }
    unsigned long long kv = keys[t];
    bool up = ((t & k) == 0);
    for(int j = ((k>>1) < 32 ? (k>>1) : 32); j >= 1; j >>= 1){
      unsigned long long pv = shflx64(kv, j);
      bool lower = ((t & j) == 0);
      unsigned long long mn = kv < pv ? kv : pv;
      unsigned long long mx = kv < pv ? pv : kv;
      kv = (lower == up) ? mn : mx;
    }
    keys[t] = kv;
    __syncthreads();
  }
  sidx[t] = (int)(keys[t] & 0xFFFFFFFFu);
}

// ---- per-head inclusive cumsum over sorted order (wave shuffle scan) ----
__global__ __launch_bounds__(1024) void k_cumsum(const float* __restrict__ delta,
     const int* __restrict__ sidx, const float* __restrict__ Bp, float* __restrict__ pfxT){
  int h = blockIdx.x, t = threadIdx.x;
  float v = delta[sidx[t]*D + h] * Bp[h];
  int lane = t & 63, w = t >> 6;
  #pragma unroll
  for(int o2 = 1; o2 < 64; o2 <<= 1){
    float nb = __shfl_up(v, o2, 64);
    if(lane >= o2) v += nb;
  }
  __shared__ float wsum[16];
  if(lane == 63) wsum[w] = v;
  __syncthreads();
  float pref = 0.f;
  #pragma unroll
  for(int i = 0; i < 16; ++i){
    float s = wsum[i];
    if(i < w) pref += s;
  }
  pfxT[h*N + t] = v + pref;   // coalesced write
}

// ---- final: y + res*Dp, LayerNorm over D, un-permute, add x ----
__global__ __launch_bounds__(128) void k_final(
    const float* __restrict__ delta, const float* __restrict__ res,
    const float* __restrict__ pfxT, const int* __restrict__ sidx,
    const float* __restrict__ s1, const float* __restrict__ s2,
    const float* __restrict__ A, const float* __restrict__ Bp,
    const float* __restrict__ Dp, const float* __restrict__ x,
    float* __restrict__ out){
  int l = blockIdx.x, h = threadIdx.x;
  int i = sidx[l];
  float dlt = delta[i*D + h];
  float dAv = expf(dlt * A[h]) * Bp[h];
  float o = dAv * s1[h] + pfxT[h*N + l] * s2[h] + res[i*D + h] * Dp[0];
  __shared__ float sm1[2], sm2[2];
  float v = o;
  v += __shfl_down(v, 32); v += __shfl_down(v, 16); v += __shfl_down(v, 8);
  v += __shfl_down(v, 4);  v += __shfl_down(v, 2);  v += __shfl_down(v, 1);
  int wid = h >> 6, lane = h & 63;
  if(lane == 0) sm1[wid] = v;
  __syncthreads();
  float mean = (sm1[0] + sm1[1]) * (1.0f/(float)D);
  float cdev = o - mean;
  float cv = cdev * cdev;
  cv += __shfl_down(cv, 32); cv += __shfl_down(cv, 16); cv += __shfl_down(cv, 8);
  cv += __shfl_down(cv, 4);  cv += __shfl_down(cv, 2);  cv += __shfl_down(cv, 1);
  if(lane == 0) sm2[wid] = cv;
  __syncthreads();
  float var = (sm2[0] + sm2[1]) * (1.0f/(float)D);
  float nrm = cdev * rsqrtf(var + 1e-5f);
  out[i*D + h] = x[i*D + h] + nrm;
}

} // namespace

extern "C" void kernel_launch(void* const* d_in, const int* in_sizes, int n_in,
                              void* d_out, int out_size, void* d_ws, size_t ws_size,
                              hipStream_t stream){
  const float* x   = (const float*)d_in[0];
  const int*   ei  = (const int*)d_in[1];
  const float* Wl  = (const float*)d_in[2];
  const float* bl  = (const float*)d_in[3];
  const float* Wr  = (const float*)d_in[4];
  const float* W1  = (const float*)d_in[5];
  const float* b1  = (const float*)d_in[6];
  const float* W2  = (const float*)d_in[7];
  const float* b2  = (const float*)d_in[8];
  const float* Wp  = (const float*)d_in[9];
  const float* A   = (const float*)d_in[10];
  const float* Bp  = (const float*)d_in[11];
  const float* Dp  = (const float*)d_in[12];
  const float* Wd  = (const float*)d_in[13];
  const float* bd  = (const float*)d_in[14];

  char* ws = (char*)d_ws;
  size_t o = 0;
  auto alloc = [&](size_t bytes)->char*{
    char* p = ws + o;
    o = (o + bytes + 255) & ~(size_t)255;
    return p;
  };
  // zero-initialized region (one memset)
  int*   cnt    = (int*)  alloc(N*4);
  int*   deg    = (int*)  alloc(N*4);
  float* s1     = (float*)alloc(D*4);
  float* s2     = (float*)alloc(D*4);
  size_t zbytes = o;
  int*   off    = (int*)  alloc((N+1)*4);
  int*   cur    = (int*)  alloc(N*4);
  int*   bucket = (int*)  alloc(E*4);
  float* scores = (float*)alloc(N*4);
  int*   sidx   = (int*)  alloc(N*4);
  float* delta  = (float*)alloc((size_t)N*D*4);
  float* res    = (float*)alloc((size_t)N*D*4);
  float* pfxT   = (float*)alloc((size_t)N*D*4);
  (void)ws_size; (void)in_sizes; (void)n_in; (void)out_size;

  hipMemsetAsync(d_ws, 0, zbytes, stream);
  k_edges1<<<(E+255)/256, 256, 0, stream>>>(ei, cnt, deg);
  k_scan  <<<1, 1024, 0, stream>>>(cnt, off, cur);
  k_edges2<<<(E+255)/256, 256, 0, stream>>>(ei, cur, bucket);
  k_fused <<<N/TILE, 256, 0, stream>>>(x, Wl, bl, Wr, W1, b1, W2, b2, Wp, Wd, bd,
                                       off, bucket, deg, delta, res, scores, s1, s2);
  k_sort  <<<1, 1024, 0, stream>>>(scores, sidx);
  k_cumsum<<<D, 1024, 0, stream>>>(delta, sidx, Bp, pfxT);
  k_final <<<N, 128, 0, stream>>>(delta, res, pfxT, sidx, s1, s2, A, Bp, Dp, x, (float*)d_out);
}